// Round 3
// baseline (1813.632 us; speedup 1.0000x reference)
//
#include <hip/hip_runtime.h>
#include <math.h>

// ---- problem dims (B=1 fixed) ----
#define S_TOK 2048
#define H_DIM 1024
#define N_HEADS 16
#define D_HEAD 128
#define Q_DIM 512
#define QKV_DIM 768          // Q + 2*D
#define NHD_ 2048            // NH*D
#define N_EXP 32
#define I_DIM 1024
#define N_LIST 6144          // S*TOPK
#define MAX_TILES 80         // bound on sum_e ceil(cnt_e/128)

typedef short bf16x8 __attribute__((ext_vector_type(8)));   // 8 bf16 = 4 VGPRs
typedef float f32x4 __attribute__((ext_vector_type(4)));    // MFMA accumulator

__device__ __forceinline__ float wave_reduce_sum(float v) {
#pragma unroll
  for (int m = 32; m >= 1; m >>= 1) v += __shfl_xor(v, m);
  return v;
}

// fp32 -> bf16 round-to-nearest-even (finite inputs)
__device__ __forceinline__ unsigned int f2bf(float f) {
  unsigned int u = __float_as_uint(f);
  unsigned int r = u + 0x7FFFu + ((u >> 16) & 1u);
  return r >> 16;
}
__device__ __forceinline__ unsigned int pack2(float a, float b) {
  return f2bf(a) | (f2bf(b) << 16);
}

// ---------------- RMSNorm (row per block) ----------------
__global__ __launch_bounds__(256) void rms_kernel(const float* __restrict__ x, int xs,
                                                  const float* __restrict__ w,
                                                  float* __restrict__ y, int ys, int cols) {
  int row = blockIdx.x, t = threadIdx.x;
  const float* xr = x + (size_t)row * xs;
  int c = t * 4;
  float4 v = {0.f, 0.f, 0.f, 0.f};
  float ss = 0.f;
  if (c < cols) {
    v = *reinterpret_cast<const float4*>(xr + c);
    ss = v.x * v.x + v.y * v.y + v.z * v.z + v.w * v.w;
  }
  ss = wave_reduce_sum(ss);
  __shared__ float red[4];
  if ((t & 63) == 0) red[t >> 6] = ss;
  __syncthreads();
  float tot = red[0] + red[1] + red[2] + red[3];
  float sc = rsqrtf(tot / (float)cols + 1e-5f);
  if (c < cols) {
    float4 wv = *reinterpret_cast<const float4*>(w + c);
    float4 o;
    o.x = v.x * sc * wv.x; o.y = v.y * sc * wv.y;
    o.z = v.z * sc * wv.z; o.w = v.w * sc * wv.w;
    *reinterpret_cast<float4*>(y + (size_t)row * ys + c) = o;
  }
}

// ---------------- bf16-MFMA tiled GEMM: C[M,N] = A[M,K]@B[K,N] (+addend) ----------------
// 128x128 tile, BK=32, 256 threads = 4 waves (2x2), per-wave 64x64 = 4x4 frags of 16x16.
// LDS layout (both operands): slot[kg*128 + r] holds 8 bf16 = elem[k0+kg*8 .. +7] of row/col r.
// Fragment reads & staging writes are 16-lane-contiguous -> conflict-free.
__global__ __launch_bounds__(256) void gemm_bf16(const float* __restrict__ A,
                                                 const float* __restrict__ B,
                                                 float* __restrict__ C,
                                                 const float* __restrict__ addend,
                                                 int M, int N, int K) {
  __shared__ uint4 As[512];   // 8 KB
  __shared__ uint4 Bs[512];   // 8 KB
  int t = threadIdx.x;
  int m0 = blockIdx.y * 128, n0 = blockIdx.x * 128;
  int lane = t & 63, wave = t >> 6;
  int wr = wave >> 1, wc = wave & 1;
  int l15 = lane & 15, lk = lane >> 4;
  f32x4 acc[4][4] = {};
  for (int k0 = 0; k0 < K; k0 += 32) {
    // stage A: p -> (m = p&127, kg = p>>7); 8 consecutive k per thread (2x float4)
#pragma unroll
    for (int i = 0; i < 2; ++i) {
      int p = i * 256 + t;
      int m = p & 127, kg = p >> 7;
      const float* ap = A + (size_t)(m0 + m) * K + k0 + kg * 8;
      float4 a0 = *reinterpret_cast<const float4*>(ap);
      float4 a1 = *reinterpret_cast<const float4*>(ap + 4);
      uint4 w;
      w.x = pack2(a0.x, a0.y); w.y = pack2(a0.z, a0.w);
      w.z = pack2(a1.x, a1.y); w.w = pack2(a1.z, a1.w);
      As[kg * 128 + m] = w;
    }
    // stage B: p -> (n = p&127, kg = p>>7); gather 8 k-rows at column n0+n
#pragma unroll
    for (int i = 0; i < 2; ++i) {
      int p = i * 256 + t;
      int n = p & 127, kg = p >> 7;
      const float* bp = B + (size_t)(k0 + kg * 8) * N + n0 + n;
      float f0 = bp[0];
      float f1 = bp[(size_t)N];
      float f2 = bp[(size_t)2 * N];
      float f3 = bp[(size_t)3 * N];
      float f4 = bp[(size_t)4 * N];
      float f5 = bp[(size_t)5 * N];
      float f6 = bp[(size_t)6 * N];
      float f7 = bp[(size_t)7 * N];
      uint4 w;
      w.x = pack2(f0, f1); w.y = pack2(f2, f3);
      w.z = pack2(f4, f5); w.w = pack2(f6, f7);
      Bs[kg * 128 + n] = w;
    }
    __syncthreads();
    bf16x8 af[4], bfr[4];
#pragma unroll
    for (int x = 0; x < 4; ++x)
      af[x] = *reinterpret_cast<const bf16x8*>(&As[lk * 128 + wr * 64 + x * 16 + l15]);
#pragma unroll
    for (int y = 0; y < 4; ++y)
      bfr[y] = *reinterpret_cast<const bf16x8*>(&Bs[lk * 128 + wc * 64 + y * 16 + l15]);
#pragma unroll
    for (int x = 0; x < 4; ++x)
#pragma unroll
      for (int y = 0; y < 4; ++y)
        acc[x][y] = __builtin_amdgcn_mfma_f32_16x16x32_bf16(af[x], bfr[y], acc[x][y], 0, 0, 0);
    __syncthreads();
  }
  // C-write: row = (lk*4 + r), col = l15 within each 16x16 fragment (m89 layout)
#pragma unroll
  for (int x = 0; x < 4; ++x) {
#pragma unroll
    for (int r = 0; r < 4; ++r) {
      int row = m0 + wr * 64 + x * 16 + lk * 4 + r;
#pragma unroll
      for (int y = 0; y < 4; ++y) {
        int col = n0 + wc * 64 + y * 16 + l15;
        float v = acc[x][y][r];
        if (addend) v += addend[(size_t)row * N + col];
        C[(size_t)row * N + col] = v;
      }
    }
  }
}

// ---------------- grouped (per-expert) bf16-MFMA GEMM over token lists ----------------
__global__ __launch_bounds__(256) void gemm_group_bf16(const float* __restrict__ X,
                                                       const float* __restrict__ Bw,
                                                       float* __restrict__ Cout,
                                                       const int* __restrict__ tileE,
                                                       const int* __restrict__ tileR0,
                                                       const int* __restrict__ nTiles,
                                                       const int* __restrict__ offs,
                                                       const int* __restrict__ list_tok,
                                                       int N, int K, int gather) {
  if ((int)blockIdx.x >= *nTiles) return;
  __shared__ uint4 As[512];
  __shared__ uint4 Bs[512];
  int e = tileE[blockIdx.x];
  int r0 = tileR0[blockIdx.x];
  int rend = offs[e + 1];
  const float* Be = Bw + (size_t)e * K * N;
  int t = threadIdx.x;
  int n0 = blockIdx.y * 128;
  int lane = t & 63, wave = t >> 6;
  int wr = wave >> 1, wc = wave & 1;
  int l15 = lane & 15, lk = lane >> 4;
  // resolve the 2 A-rows this thread stages (constant over k-loop)
  int srow_[2]; bool valid_[2];
#pragma unroll
  for (int i = 0; i < 2; ++i) {
    int p = i * 256 + t;
    int m = p & 127;
    int lrow = r0 + m;
    valid_[i] = lrow < rend;
    srow_[i] = valid_[i] ? (gather ? list_tok[lrow] : lrow) : 0;
  }
  f32x4 acc[4][4] = {};
  for (int k0 = 0; k0 < K; k0 += 32) {
#pragma unroll
    for (int i = 0; i < 2; ++i) {
      int p = i * 256 + t;
      int m = p & 127, kg = p >> 7;
      uint4 w = {0u, 0u, 0u, 0u};
      if (valid_[i]) {
        const float* ap = X + (size_t)srow_[i] * K + k0 + kg * 8;
        float4 a0 = *reinterpret_cast<const float4*>(ap);
        float4 a1 = *reinterpret_cast<const float4*>(ap + 4);
        w.x = pack2(a0.x, a0.y); w.y = pack2(a0.z, a0.w);
        w.z = pack2(a1.x, a1.y); w.w = pack2(a1.z, a1.w);
      }
      As[kg * 128 + m] = w;
    }
#pragma unroll
    for (int i = 0; i < 2; ++i) {
      int p = i * 256 + t;
      int n = p & 127, kg = p >> 7;
      const float* bp = Be + (size_t)(k0 + kg * 8) * N + n0 + n;
      float f0 = bp[0];
      float f1 = bp[(size_t)N];
      float f2 = bp[(size_t)2 * N];
      float f3 = bp[(size_t)3 * N];
      float f4 = bp[(size_t)4 * N];
      float f5 = bp[(size_t)5 * N];
      float f6 = bp[(size_t)6 * N];
      float f7 = bp[(size_t)7 * N];
      uint4 w;
      w.x = pack2(f0, f1); w.y = pack2(f2, f3);
      w.z = pack2(f4, f5); w.w = pack2(f6, f7);
      Bs[kg * 128 + n] = w;
    }
    __syncthreads();
    bf16x8 af[4], bfr[4];
#pragma unroll
    for (int x = 0; x < 4; ++x)
      af[x] = *reinterpret_cast<const bf16x8*>(&As[lk * 128 + wr * 64 + x * 16 + l15]);
#pragma unroll
    for (int y = 0; y < 4; ++y)
      bfr[y] = *reinterpret_cast<const bf16x8*>(&Bs[lk * 128 + wc * 64 + y * 16 + l15]);
#pragma unroll
    for (int x = 0; x < 4; ++x)
#pragma unroll
      for (int y = 0; y < 4; ++y)
        acc[x][y] = __builtin_amdgcn_mfma_f32_16x16x32_bf16(af[x], bfr[y], acc[x][y], 0, 0, 0);
    __syncthreads();
  }
#pragma unroll
  for (int x = 0; x < 4; ++x) {
#pragma unroll
    for (int r = 0; r < 4; ++r) {
      int orow = r0 + wr * 64 + x * 16 + lk * 4 + r;
      if (orow < rend) {
#pragma unroll
        for (int y = 0; y < 4; ++y) {
          int col = n0 + wc * 64 + y * 16 + l15;
          Cout[(size_t)orow * N + col] = acc[x][y][r];
        }
      }
    }
  }
}

// ---------------- RoPE for q ([S][16][128] in-place) and k (from qkv -> kr) ----------------
__global__ __launch_bounds__(256) void rope_kernel(float* __restrict__ qp,
                                                   const float* __restrict__ qkv,
                                                   float* __restrict__ kr,
                                                   const int* __restrict__ pos) {
  int s = blockIdx.x, t = threadIdx.x;
  __shared__ float cs[64], sn[64];
  float fp = (float)pos[s];
  if (t < 64) {
    float inv = powf(500000.0f, -(float)t * (1.0f / 64.0f));  // THETA^(-2i/128)
    float f = fp * inv;
    cs[t] = cosf(f);
    sn[t] = sinf(f);
  }
  __syncthreads();
  if (t < 64) {
    float x1 = qkv[(size_t)s * QKV_DIM + 512 + t];
    float x2 = qkv[(size_t)s * QKV_DIM + 512 + 64 + t];
    kr[(size_t)s * 128 + t] = x1 * cs[t] - x2 * sn[t];
    kr[(size_t)s * 128 + 64 + t] = x2 * cs[t] + x1 * sn[t];
  }
  for (int p = t; p < N_HEADS * 64; p += 256) {
    int hh = p >> 6, i = p & 63;
    float* qr = qp + (size_t)s * NHD_ + hh * 128;
    float x1 = qr[i], x2 = qr[64 + i];
    qr[i] = x1 * cs[i] - x2 * sn[i];
    qr[64 + i] = x2 * cs[i] + x1 * sn[i];
  }
}

// ---------------- causal MQA flash attention, fp32, 64x64 tiles ----------------
__global__ __launch_bounds__(256) void attn_kernel(const float* __restrict__ q,
                                                   const float* __restrict__ k,
                                                   const float* __restrict__ qkv,
                                                   float* __restrict__ o) {
  __shared__ float Qs[64][132];
  __shared__ float Ks[64][132];
  __shared__ float Vs[64][132];
  __shared__ float Ps[64][68];
  int h = blockIdx.y, qi = blockIdx.x, s0 = qi * 64;
  int t = threadIdx.x, tx = t & 15, ty = t >> 4;
  for (int i = t; i < 64 * 32; i += 256) {
    int r = i >> 5, c = (i & 31) * 4;
    *reinterpret_cast<float4*>(&Qs[r][c]) =
        *reinterpret_cast<const float4*>(q + (size_t)(s0 + r) * NHD_ + h * D_HEAD + c);
  }
  float O[4][8] = {};
  float mrow[4], lrow[4];
#pragma unroll
  for (int i = 0; i < 4; ++i) { mrow[i] = -1e30f; lrow[i] = 0.f; }
  for (int j = 0; j <= qi; ++j) {
    int t0 = j * 64;
    for (int i = t; i < 64 * 32; i += 256) {
      int r = i >> 5, c = (i & 31) * 4;
      *reinterpret_cast<float4*>(&Ks[r][c]) =
          *reinterpret_cast<const float4*>(k + (size_t)(t0 + r) * D_HEAD + c);
      *reinterpret_cast<float4*>(&Vs[r][c]) =
          *reinterpret_cast<const float4*>(qkv + (size_t)(t0 + r) * QKV_DIM + 640 + c);
    }
    __syncthreads();
    float sc[4][4] = {};
#pragma unroll 4
    for (int kv = 0; kv < 32; ++kv) {
      float4 qv[4], kk[4];
#pragma unroll
      for (int i = 0; i < 4; ++i) qv[i] = *reinterpret_cast<const float4*>(&Qs[ty * 4 + i][kv * 4]);
#pragma unroll
      for (int c = 0; c < 4; ++c) kk[c] = *reinterpret_cast<const float4*>(&Ks[tx * 4 + c][kv * 4]);
#pragma unroll
      for (int i = 0; i < 4; ++i)
#pragma unroll
        for (int c = 0; c < 4; ++c) {
          sc[i][c] = fmaf(qv[i].x, kk[c].x, sc[i][c]);
          sc[i][c] = fmaf(qv[i].y, kk[c].y, sc[i][c]);
          sc[i][c] = fmaf(qv[i].z, kk[c].z, sc[i][c]);
          sc[i][c] = fmaf(qv[i].w, kk[c].w, sc[i][c]);
        }
    }
    const float scale = 0.08838834764831845f;  // 1/sqrt(128)
    bool full = (j < qi);
#pragma unroll
    for (int i = 0; i < 4; ++i) {
      int srow = s0 + ty * 4 + i;
#pragma unroll
      for (int c = 0; c < 4; ++c) {
        int tcol = t0 + tx * 4 + c;
        sc[i][c] = (full || tcol <= srow) ? sc[i][c] * scale : -1e30f;
      }
    }
#pragma unroll
    for (int i = 0; i < 4; ++i) {
      float m = fmaxf(fmaxf(sc[i][0], sc[i][1]), fmaxf(sc[i][2], sc[i][3]));
#pragma unroll
      for (int d = 1; d < 16; d <<= 1) m = fmaxf(m, __shfl_xor(m, d));
      float mnew = fmaxf(mrow[i], m);
      float alpha = expf(mrow[i] - mnew);
      float ps = 0.f;
#pragma unroll
      for (int c = 0; c < 4; ++c) {
        float p = expf(sc[i][c] - mnew);
        sc[i][c] = p;
        ps += p;
      }
#pragma unroll
      for (int d = 1; d < 16; d <<= 1) ps += __shfl_xor(ps, d);
      lrow[i] = lrow[i] * alpha + ps;
      mrow[i] = mnew;
#pragma unroll
      for (int dd = 0; dd < 8; ++dd) O[i][dd] *= alpha;
      *reinterpret_cast<float4*>(&Ps[ty * 4 + i][tx * 4]) =
          make_float4(sc[i][0], sc[i][1], sc[i][2], sc[i][3]);
    }
    __syncthreads();
#pragma unroll 4
    for (int tt = 0; tt < 64; ++tt) {
      float4 v0 = *reinterpret_cast<const float4*>(&Vs[tt][tx * 8]);
      float4 v1 = *reinterpret_cast<const float4*>(&Vs[tt][tx * 8 + 4]);
#pragma unroll
      for (int i = 0; i < 4; ++i) {
        float p = Ps[ty * 4 + i][tt];
        O[i][0] = fmaf(p, v0.x, O[i][0]);
        O[i][1] = fmaf(p, v0.y, O[i][1]);
        O[i][2] = fmaf(p, v0.z, O[i][2]);
        O[i][3] = fmaf(p, v0.w, O[i][3]);
        O[i][4] = fmaf(p, v1.x, O[i][4]);
        O[i][5] = fmaf(p, v1.y, O[i][5]);
        O[i][6] = fmaf(p, v1.z, O[i][6]);
        O[i][7] = fmaf(p, v1.w, O[i][7]);
      }
    }
    __syncthreads();
  }
#pragma unroll
  for (int i = 0; i < 4; ++i) {
    float inv = 1.f / lrow[i];
    float* op = o + (size_t)(s0 + ty * 4 + i) * NHD_ + h * D_HEAD + tx * 8;
#pragma unroll
    for (int dd = 0; dd < 8; ++dd) op[dd] = O[i][dd] * inv;
  }
}

// ---------------- SwiGLU: act[r][i] = silu(gu[r][i]) * gu[r][I+i] ----------------
__global__ __launch_bounds__(256) void silu_mul_kernel(const float* __restrict__ gu,
                                                       float* __restrict__ act) {
  int r = blockIdx.x, c = threadIdx.x * 4;
  float4 g = *reinterpret_cast<const float4*>(gu + (size_t)r * 2048 + c);
  float4 u = *reinterpret_cast<const float4*>(gu + (size_t)r * 2048 + 1024 + c);
  float4 a;
  a.x = g.x / (1.f + expf(-g.x)) * u.x;
  a.y = g.y / (1.f + expf(-g.y)) * u.y;
  a.z = g.z / (1.f + expf(-g.z)) * u.z;
  a.w = g.w / (1.f + expf(-g.w)) * u.w;
  *reinterpret_cast<float4*>(act + (size_t)r * 1024 + c) = a;
}

// ---------------- router: logits -> softmax -> top3 (normalized) ----------------
__global__ __launch_bounds__(256) void router_kernel(const float* __restrict__ x,
                                                     const float* __restrict__ wr,
                                                     float* __restrict__ topw,
                                                     int* __restrict__ topi) {
  int wv = threadIdx.x >> 6, lane = threadIdx.x & 63;
  int n = blockIdx.x * 4 + wv;
  float acc[32];
#pragma unroll
  for (int e = 0; e < 32; ++e) acc[e] = 0.f;
  const float* xr = x + (size_t)n * H_DIM;
  for (int hh = lane; hh < H_DIM; hh += 64) {
    float xv = xr[hh];
    const float4* w4 = reinterpret_cast<const float4*>(wr + (size_t)hh * 32);
#pragma unroll
    for (int e4 = 0; e4 < 8; ++e4) {
      float4 w = w4[e4];
      acc[e4 * 4 + 0] = fmaf(xv, w.x, acc[e4 * 4 + 0]);
      acc[e4 * 4 + 1] = fmaf(xv, w.y, acc[e4 * 4 + 1]);
      acc[e4 * 4 + 2] = fmaf(xv, w.z, acc[e4 * 4 + 2]);
      acc[e4 * 4 + 3] = fmaf(xv, w.w, acc[e4 * 4 + 3]);
    }
  }
#pragma unroll
  for (int e = 0; e < 32; ++e) {
#pragma unroll
    for (int m = 1; m < 64; m <<= 1) acc[e] += __shfl_xor(acc[e], m);
  }
  if (lane == 0) {
    float mx = acc[0];
#pragma unroll
    for (int e = 1; e < 32; ++e) mx = fmaxf(mx, acc[e]);
    float p[32];
#pragma unroll
    for (int e = 0; e < 32; ++e) p[e] = expf(acc[e] - mx);
    float tw[3]; int ti[3];
#pragma unroll
    for (int j = 0; j < 3; ++j) {
      float bv = -1.f; int bi = 0;
      for (int e = 0; e < 32; ++e)
        if (p[e] > bv) { bv = p[e]; bi = e; }   // strict > => first index on tie
      tw[j] = bv; ti[j] = bi; p[bi] = -2.f;
    }
    float tn = tw[0] + tw[1] + tw[2];
#pragma unroll
    for (int j = 0; j < 3; ++j) {
      topw[n * 3 + j] = tw[j] / tn;
      topi[n * 3 + j] = ti[j];
    }
  }
}

// ---------------- MoE routing plumbing ----------------
__global__ void zero_cnt(int* cnt) { if (threadIdx.x < 32) cnt[threadIdx.x] = 0; }

__global__ __launch_bounds__(256) void count_kernel(const int* __restrict__ topi,
                                                    int* __restrict__ cnt) {
  int i = blockIdx.x * 256 + threadIdx.x;
  if (i < N_LIST) atomicAdd(&cnt[topi[i]], 1);
}

__global__ void scan_tiles(const int* __restrict__ cnt, int* __restrict__ offs,
                           int* __restrict__ tileE, int* __restrict__ tileR0,
                           int* __restrict__ nTiles, int* __restrict__ cursor) {
  if (threadIdx.x != 0 || blockIdx.x != 0) return;
  int o = 0, nt = 0;
  for (int e = 0; e < 32; ++e) {
    offs[e] = o;
    cursor[e] = 0;
    int c = cnt[e];
    for (int r = 0; r < c; r += 128) { tileE[nt] = e; tileR0[nt] = o + r; ++nt; }
    o += c;
  }
  offs[32] = o;
  *nTiles = nt;
}

__global__ __launch_bounds__(256) void scatter_kernel(const int* __restrict__ topi,
                                                      const int* __restrict__ offs,
                                                      int* __restrict__ cursor,
                                                      int* __restrict__ list_tok,
                                                      int* __restrict__ slotpos) {
  int i = blockIdx.x * 256 + threadIdx.x;
  if (i < N_LIST) {
    int e = topi[i];
    int p = atomicAdd(&cursor[e], 1);
    int row = offs[e] + p;
    list_tok[row] = i / 3;
    slotpos[i] = row;
  }
}

// ---------------- final combine ----------------
__global__ __launch_bounds__(256) void combine_kernel(const float* __restrict__ shr,
                                                      const float* __restrict__ r2,
                                                      const float* __restrict__ de,
                                                      const float* __restrict__ topw,
                                                      const int* __restrict__ slotpos,
                                                      float* __restrict__ out) {
  int n = blockIdx.x, c = threadIdx.x * 4;
  float w0 = topw[n * 3], w1 = topw[n * 3 + 1], w2 = topw[n * 3 + 2];
  const float* d0 = de + (size_t)slotpos[n * 3] * 1024;
  const float* d1 = de + (size_t)slotpos[n * 3 + 1] * 1024;
  const float* d2 = de + (size_t)slotpos[n * 3 + 2] * 1024;
  float4 a = *reinterpret_cast<const float4*>(shr + (size_t)n * 1024 + c);
  float4 b = *reinterpret_cast<const float4*>(r2 + (size_t)n * 1024 + c);
  float4 e0 = *reinterpret_cast<const float4*>(d0 + c);
  float4 e1 = *reinterpret_cast<const float4*>(d1 + c);
  float4 e2 = *reinterpret_cast<const float4*>(d2 + c);
  float4 r;
  r.x = a.x + b.x + w0 * e0.x + w1 * e1.x + w2 * e2.x;
  r.y = a.y + b.y + w0 * e0.y + w1 * e1.y + w2 * e2.y;
  r.z = a.z + b.z + w0 * e0.z + w1 * e1.z + w2 * e2.z;
  r.w = a.w + b.w + w0 * e0.w + w1 * e1.w + w2 * e2.w;
  *reinterpret_cast<float4*>(out + (size_t)n * 1024 + c) = r;
}

extern "C" void kernel_launch(void* const* d_in, const int* in_sizes, int n_in,
                              void* d_out, int out_size, void* d_ws, size_t ws_size,
                              hipStream_t stream) {
  (void)in_sizes; (void)n_in; (void)out_size; (void)ws_size;
  const float* hidden   = (const float*)d_in[0];
  const float* w_in     = (const float*)d_in[1];
  const float* w_qkv    = (const float*)d_in[2];
  const float* w_inter  = (const float*)d_in[3];
  const float* w_q      = (const float*)d_in[4];
  const float* w_o      = (const float*)d_in[5];
  const float* w_post   = (const float*)d_in[6];
  const float* w_guse   = (const float*)d_in[7];
  const float* w_dse    = (const float*)d_in[8];
  const float* w_router = (const float*)d_in[9];
  const float* w_gue    = (const float*)d_in[10];
  const float* w_de     = (const float*)d_in[11];
  const int*   pos      = (const int*)d_in[12];
  float* out = (float*)d_out;

  // ---- workspace carve (floats), phase-based aliasing ----
  float* ws = (float*)d_ws;
  size_t off = 0;
  auto alloc = [&](size_t n) { float* p = ws + off; off += (n + 63) & ~(size_t)63; return p; };
  float* bufA = alloc(13369344);            // attention-phase scratch, later MoE gu_e / de
  float* xn1 = bufA;                        // [2048][1024]
  float* qkv = bufA + 2097152;              // [2048][768]
  float* qn  = bufA + 3670016;              // [2048][512]
  float* qp  = bufA + 4718592;              // [2048][2048]
  float* kr  = bufA + 8912896;              // [2048][128]
  float* ao  = bufA + 9175040;              // [2048][2048]
  float* gu_e = bufA;                       // alias: [6144][2048]
  float* de   = bufA;                       // alias: [6144][1024]
  float* r2   = alloc(2097152);             // [2048][1024] residual-2
  float* xn2  = alloc(2097152);             // [2048][1024]
  float* guact = alloc(6291456);
  float* gu   = guact;                      // [2048][2048]
  float* act  = guact + 4194304;            // [2048][1024]
  float* act_e = guact;                     // alias: [6144][1024]
  float* shr  = alloc(2097152);             // [2048][1024]
  float* topw = alloc(6144);
  int* ip = (int*)(ws + off);
  int* topi     = ip; ip += 6144;
  int* slotpos  = ip; ip += 6144;
  int* list_tok = ip; ip += 6144;
  int* cnt      = ip; ip += 32;
  int* offs     = ip; ip += 33;
  int* cursor   = ip; ip += 33;
  int* tileE    = ip; ip += MAX_TILES;
  int* tileR0   = ip; ip += MAX_TILES;
  int* nTiles   = ip; ip += 1;

  dim3 b256(256);
  // 1. pre-attention norm
  rms_kernel<<<2048, b256, 0, stream>>>(hidden, 1024, w_in, xn1, 1024, 1024);
  // 2. qkv projection (bf16 MFMA)
  gemm_bf16<<<dim3(6, 16), b256, 0, stream>>>(xn1, w_qkv, qkv, nullptr, 2048, 768, 1024);
  // 3. q inner norm
  rms_kernel<<<2048, b256, 0, stream>>>(qkv, 768, w_inter, qn, 512, 512);
  // 4. q up-projection
  gemm_bf16<<<dim3(16, 16), b256, 0, stream>>>(qn, w_q, qp, nullptr, 2048, 2048, 512);
  // 5. rope q (in-place) + k
  rope_kernel<<<2048, b256, 0, stream>>>(qp, qkv, kr, pos);
  // 6. causal MQA flash attention (fp32 this round)
  attn_kernel<<<dim3(32, 16), b256, 0, stream>>>(qp, kr, qkv, ao);
  // 7. output projection + residual
  gemm_bf16<<<dim3(8, 16), b256, 0, stream>>>(ao, w_o, r2, hidden, 2048, 1024, 2048);
  // 8. post-attention norm
  rms_kernel<<<2048, b256, 0, stream>>>(r2, 1024, w_post, xn2, 1024, 1024);
  // 9-11. shared expert FFN
  gemm_bf16<<<dim3(16, 16), b256, 0, stream>>>(xn2, w_guse, gu, nullptr, 2048, 2048, 1024);
  silu_mul_kernel<<<2048, b256, 0, stream>>>(gu, act);
  gemm_bf16<<<dim3(8, 16), b256, 0, stream>>>(act, w_dse, shr, nullptr, 2048, 1024, 1024);
  // 12. router + top3
  router_kernel<<<512, b256, 0, stream>>>(xn2, w_router, topw, topi);
  // 13. build per-expert token lists
  zero_cnt<<<1, 64, 0, stream>>>(cnt);
  count_kernel<<<24, b256, 0, stream>>>(topi, cnt);
  scan_tiles<<<1, 64, 0, stream>>>(cnt, offs, tileE, tileR0, nTiles, cursor);
  scatter_kernel<<<24, b256, 0, stream>>>(topi, offs, cursor, list_tok, slotpos);
  // 14-16. sparse MoE (grouped per-expert bf16 GEMMs)
  gemm_group_bf16<<<dim3(MAX_TILES, 16), b256, 0, stream>>>(xn2, w_gue, gu_e, tileE, tileR0,
                                                            nTiles, offs, list_tok, 2048, 1024, 1);
  silu_mul_kernel<<<6144, b256, 0, stream>>>(gu_e, act_e);
  gemm_group_bf16<<<dim3(MAX_TILES, 8), b256, 0, stream>>>(act_e, w_de, de, tileE, tileR0,
                                                           nTiles, offs, list_tok, 1024, 1024, 0);
  // 17. combine: share + resid2 + weighted expert outputs
  combine_kernel<<<2048, b256, 0, stream>>>(shr, r2, de, topw, slotpos, out);
}